// Round 9
// baseline (2615.969 us; speedup 1.0000x reference)
//
#include <hip/hip_runtime.h>
#include <math.h>

#define NCB 7
#define CBK 1024
#define CD  8
#define BB  16
#define DD  256
#define TT  8192
#define BT  (BB*TT)          // 131072 positions

typedef float v2f __attribute__((ext_vector_type(2)));
typedef float v4f __attribute__((ext_vector_type(4)));

static constexpr size_t ZQN  = (size_t)BB * DD * TT;   // 33554432
static constexpr size_t IDX0 = ZQN + 2;

// ---- workspace float offsets --------------------------------------------
#define WS_WTINT  16
#define WS_WTOUTT 16400
#define WS_OBT    32784
#define WS_APK    34832
#define WS_UVEC   37968
#define WS_CBP    38032      // records now 20 floats (80 B): 7*512*20 = 71680

// ---------------------------------------------------------------- prep1 ----
__global__ void rvq_prep1(const float* __restrict__ in_v, const float* __restrict__ in_g,
                          const float* __restrict__ out_v, const float* __restrict__ out_g,
                          const float* __restrict__ out_b, const float* __restrict__ cb,
                          float* __restrict__ ws, double* __restrict__ lossAcc)
{
#pragma clang fp contract(off)
  int gid = blockIdx.x * blockDim.x + threadIdx.x;
  if (gid == 0) *lossAcc = 0.0;
  if (gid < NCB*DD*CD) {                       // WTINT[d][i*8+c]
    int i = gid / (DD*CD); int rem = gid % (DD*CD); int d = rem / CD; int c = rem % CD;
    const float* vrow = in_v + ((size_t)i*CD + c) * DD;       // in_v [NCB][CD][DD]
    double acc = 0.0;
    for (int q = 0; q < DD; ++q) { double v = vrow[q]; acc += v*v; }
    float nf = (float)sqrt(acc);
    ws[WS_WTINT + d*64 + i*8 + c] = (in_g[i*CD + c] * vrow[d]) / nf;
  } else if (gid < 2*NCB*DD*CD) {              // WTOUTT[d][i*8+c]
    int e = gid - NCB*DD*CD;
    int i = e / (DD*CD); int rem = e % (DD*CD); int d = rem / CD; int c = rem % CD;
    const float* vrow = out_v + ((size_t)i*DD + d)*CD;        // out_v [NCB][DD][CD]
    double acc = 0.0;
    for (int q = 0; q < CD; ++q) { double v = vrow[q]; acc += v*v; }
    float nf = (float)sqrt(acc);
    ws[WS_WTOUTT + d*64 + i*8 + c] = (out_g[i*DD + d] * vrow[c]) / nf;
  } else if (gid < 2*NCB*DD*CD + DD*8) {       // OBT[d][i]
    int e = gid - 2*NCB*DD*CD;
    int d = e >> 3, i = e & 7;
    ws[WS_OBT + d*8 + i] = (i < NCB) ? out_b[i*DD + d] : 0.f;
  } else if (gid < 2*NCB*DD*CD + DD*8 + NCB*CBK) {  // CBP paired records (20 f)
    int e = gid - 2*NCB*DD*CD - DD*8;
    int i = e / CBK; int k = e % CBK;
    const float* row = cb + ((size_t)i*CBK + k)*CD;
    double acc = 0.0;
    for (int c = 0; c < CD; ++c) { double v = row[c]; acc += v*v; }
    float nf = fmaxf((float)sqrt(acc), 1e-12f);
    float* rec = ws + WS_CBP + ((size_t)i*512 + (k >> 1))*20;
    int h = k & 1;
    float c2 = 0.f;
    for (int c = 0; c < CD; ++c) {
      float cn = row[c] / nf;            // IEEE division, mirrors np
      rec[2*c + h] = cn;
      float s = cn*cn; c2 += s;          // square-then-add (contract off)
    }
    rec[16 + h] = c2;
    if (h == 0) { rec[18] = 0.f; rec[19] = 0.f; }   // pad (defined values)
  }
}

// ---------------------------------------------------------------- prep2 ----
__global__ void rvq_prep2(const float* __restrict__ in_b, const float* __restrict__ out_b,
                          float* __restrict__ ws)
{
#pragma clang fp contract(off)
  int gid = blockIdx.x * blockDim.x + threadIdx.x;
  if (gid < 49*64) {
    int pair = gid / 64; int j = pair / 7; int i2 = pair % 7;
    int e = gid % 64; int cp = e >> 3; int c = e & 7;
    float v = 0.f;
    if (j < i2) {
      double acc = 0.0;
      for (int d = 0; d < DD; ++d)
        acc += (double)ws[WS_WTINT + d*64 + i2*8 + c] * (double)ws[WS_WTOUTT + d*64 + j*8 + cp];
      v = (float)acc;
    }
    ws[WS_APK + pair*64 + cp*8 + c] = v;
  } else if (gid < 49*64 + 64) {
    int e = gid - 49*64; int i = e >> 3; int c = e & 7;
    float v = 0.f;
    if (i < NCB) {
      double s = (double)in_b[i*CD + c];
      for (int j = 0; j < i; ++j)
        for (int d = 0; d < DD; ++d)
          s -= (double)ws[WS_WTINT + d*64 + i*8 + c] * (double)out_b[j*DD + d];
      v = (float)s;
    }
    ws[WS_UVEC + e] = v;
  }
}

// ---------------------------------------------------------------- quant ----
// Structure identical to round-8 (2 position-groups x 2 halves). ONE change:
// all streamed weight/codebook reads go through the VECTOR memory path (an
// opaque VGPR zero added to the base pointer) instead of s_load. SMEM returns
// out-of-order -> every use forces lgkmcnt(0) full drain (no pipelining);
// VMEM is vmcnt-counted with partial waits -> compiler software-pipelines.
// Same-address-across-lanes loads coalesce to one L2 transaction (broadcast).
__launch_bounds__(256)
__global__ void rvq_quant(const float* __restrict__ z,
                          const float* __restrict__ cb,
                          const int* __restrict__ nqp,
                          const float* __restrict__ ws,
                          float* __restrict__ out, double* __restrict__ lossAcc)
{
#pragma clang fp contract(off)
  const int tid = threadIdx.x;
  const int p   = tid & 63;
  const int h   = __builtin_amdgcn_readfirstlane((tid >> 6) & 1);
  const int g   = __builtin_amdgcn_readfirstlane(tid >> 7);
  const int blk = blockIdx.x;
  const int b   = blk >> 6;                   // 64 blocks per batch
  const int t   = ((blk & 63) << 7) + g*64 + p;
  int nqc = *nqp; nqc = nqc < 0 ? 0 : (nqc > NCB ? NCB : nqc);

  // opaque vector zero: forces VMEM (per-lane) addressing on derived pointers
  uint32_t vz;
  asm volatile("v_mov_b32 %0, 0" : "=v"(vz));
  const float* WTINT  = (const float*)((const char*)(ws + WS_WTINT)  + vz);
  const float* WTOUTT = (const float*)((const char*)(ws + WS_WTOUTT) + vz);
  const float* APK    = (const float*)((const char*)(ws + WS_APK)    + vz);
  const float* CBP    = (const float*)((const char*)(ws + WS_CBP)    + vz);
  const float* OBT    = ws + WS_OBT;
  const float* UVEC   = ws + WS_UVEC;

  __shared__ v4f   pex[2][14][64];   // 28.7 KB: P-combine buffer
  __shared__ float scb[2][2][64];    // per-half best
  __shared__ int   sck[2][2][64];    // per-half argmin

  // ---- P-phase: partial over this half's d-range, ascending d
  v2f ze2[28];
#pragma unroll
  for (int x = 0; x < 28; ++x) ze2[x] = (v2f){0.f, 0.f};
  {
    const float* zc0 = z + (size_t)b*DD*TT + (size_t)(h*128)*TT + t;
#pragma unroll 2
    for (int j = 0; j < 128; ++j) {
      float zv = zc0[(size_t)j*TT];
      const v2f* wv = (const v2f*)(WTINT + (h*128 + j)*64);
      v2f zb = (v2f){zv, zv};
#pragma unroll
      for (int x = 0; x < 28; ++x)
        ze2[x] = __builtin_elementwise_fma(wv[x], zb, ze2[x]);
    }
  }

  // ---- combine halves (IEEE add commutative -> bitwise-identical sums)
  if (h) {
#pragma unroll
    for (int x = 0; x < 14; ++x)
      pex[g][x][p] = (v4f){ze2[2*x].x, ze2[2*x].y, ze2[2*x+1].x, ze2[2*x+1].y};
  }
  __syncthreads();
  if (!h) {
#pragma unroll
    for (int x = 0; x < 14; ++x) {
      v4f o = pex[g][x][p];
      ze2[2*x]   = ze2[2*x]   + (v2f){o.x, o.y};
      ze2[2*x+1] = ze2[2*x+1] + (v2f){o.z, o.w};
      pex[g][x][p] = (v4f){ze2[2*x].x, ze2[2*x].y, ze2[2*x+1].x, ze2[2*x+1].y};
    }
  }
  __syncthreads();
  if (h) {
#pragma unroll
    for (int x = 0; x < 14; ++x) {
      v4f o = pex[g][x][p];
      ze2[2*x]   = (v2f){o.x, o.y};
      ze2[2*x+1] = (v2f){o.z, o.w};
    }
  }
  {
    const v2f* uv = (const v2f*)UVEC;
#pragma unroll
    for (int x = 0; x < 28; ++x) ze2[x] = ze2[x] + uv[x];
  }

  double lacc = 0.0;
  v2f zh[NCB][4];                      // zst history (static indexing only)

#pragma unroll
  for (int i = 0; i < NCB; ++i) {
    // ---- finalize z_e_i, l2-normalize (validated chain shape)
    float zef[CD], en[CD];
#pragma unroll
    for (int x = 0; x < 4; ++x) { zef[2*x] = ze2[i*4 + x].x; zef[2*x + 1] = ze2[i*4 + x].y; }
    float ss = 0.f;
#pragma unroll
    for (int c = 0; c < CD; ++c) { float sq = zef[c]*zef[c]; ss += sq; }
    float den = fmaxf(sqrtf(ss), 1e-12f);
    float a2 = 0.f;
#pragma unroll
    for (int c = 0; c < CD; ++c) {
      float en_ = zef[c] / den;        // IEEE division, mirrors np
      en[c] = en_;
      float sq = en_*en_; a2 += sq;
    }

    // ---- scan this half's 256 pairs: two 128-pair streams, VMEM records
    v2f enb[CD];
#pragma unroll
    for (int c = 0; c < CD; ++c) enb[c] = (v2f){en[c], en[c]};
    const v2f a2b = (v2f){a2, a2};
    const v2f n2b = (v2f){-2.f, -2.f};
    const v2f* crow = (const v2f*)(CBP + ((size_t)i*512 + h*256)*20);
    float best0 = 3.0e38f, best1 = 3.0e38f; int bk0 = 0, bk1 = 0;
#pragma unroll 2
    for (int qq = 0; qq < 128; ++qq) {
      const v2f* r0 = crow + qq*10;           // 80 B record stride
      const v2f* r1 = crow + (128 + qq)*10;
      v2f m0 = r0[0]*enb[0];
      v2f m1 = r1[0]*enb[0];
#pragma unroll
      for (int c = 1; c < CD; ++c) {
        m0 = __builtin_elementwise_fma(r0[c], enb[c], m0);
        m1 = __builtin_elementwise_fma(r1[c], enb[c], m1);
      }
      v2f d0 = __builtin_elementwise_fma(n2b, m0, a2b); d0 = d0 + r0[8];
      v2f d1 = __builtin_elementwise_fma(n2b, m1, a2b); d1 = d1 + r1[8];
      int kb0 = (h*256 + qq)*2;
      int kb1 = (h*256 + 128 + qq)*2;
      bool l;
      l = d0.x < best0; best0 = l ? d0.x : best0; bk0 = l ? kb0     : bk0;
      l = d0.y < best0; best0 = l ? d0.y : best0; bk0 = l ? kb0 + 1 : bk0;
      l = d1.x < best1; best1 = l ? d1.x : best1; bk1 = l ? kb1     : bk1;
      l = d1.y < best1; best1 = l ? d1.y : best1; bk1 = l ? kb1 + 1 : bk1;
    }
    // merge streams (stream0 ks < stream1 ks -> strict <)
    bool ltS = best1 < best0;
    float bestT = ltS ? best1 : best0;
    int   bkT   = ltS ? bk1   : bk0;

    // ---- cross-half merge via LDS (h=0 range < h=1 range, strict <)
    scb[g][h][p] = bestT; sck[g][h][p] = bkT;
    __syncthreads();
    float bA = scb[g][0][p]; int kA = sck[g][0][p];
    float bB = scb[g][1][p]; int kB = sck[g][1][p];
    bool ltH = bB < bA;
    int k = ltH ? kB : kA;
    __syncthreads();     // protects scb/sck reuse at next i

    // ---- gather raw code, STE, loss, idx (validated chain shape)
    const float* qrow = cb + ((size_t)i*CBK + k)*CD;
    v4f qa = ((const v4f*)qrow)[0];
    v4f qb = ((const v4f*)qrow)[1];
    float zcv[CD] = {qa.x, qa.y, qa.z, qa.w, qb.x, qb.y, qb.z, qb.w};
    float zst[CD];
    float sloc = 0.f;
#pragma unroll
    for (int c = 0; c < CD; ++c) {
      float zv = zef[c];
      zst[c] = zv + (zcv[c] - zv);     // z_e + (z_q_c - z_e), np rounding
      float df = zv - zcv[c];
      float sq = df*df; sloc += sq;
    }
    if (h == 0) {
      if (i < nqc) lacc += (double)sloc;
      out[IDX0 + ((size_t)b*NCB + i)*TT + t] = (float)k;
    }
#pragma unroll
    for (int x = 0; x < 4; ++x) zh[i][x] = (v2f){zst[2*x], zst[2*x + 1]};

    // ---- push correction into all future ze accumulators (duplicated)
#pragma unroll
    for (int i2 = i + 1; i2 < NCB; ++i2) {
      const v2f* av = (const v2f*)(APK + (size_t)(i*7 + i2)*64);
      v2f corr[4];
#pragma unroll
      for (int x = 0; x < 4; ++x) corr[x] = av[x] * (v2f){zst[0], zst[0]};
#pragma unroll
      for (int cp = 1; cp < CD; ++cp) {
        v2f zb = (v2f){zst[cp], zst[cp]};
#pragma unroll
        for (int x = 0; x < 4; ++x)
          corr[x] = __builtin_elementwise_fma(av[cp*4 + x], zb, corr[x]);
      }
#pragma unroll
      for (int x = 0; x < 4; ++x) ze2[i2*4 + x] = ze2[i2*4 + x] - corr[x];
    }
  }

  // ---- out-projection: this half writes d in [h*128, h*128+128)
  {
    float* zq = out + (size_t)b*DD*TT + t;
    const int dbase = h*128;
#pragma unroll 2
    for (int j = 0; j < 128; ++j) {
      const int d = dbase + j;
      const v2f* wr = (const v2f*)(WTOUTT + d*64);
      const float* obr = OBT + d*8;
      float acc = 0.f;
#pragma unroll
      for (int i = 0; i < NCB; ++i) {
        if (i < nqc) {
          v2f mm = wr[i*4] * zh[i][0];
          mm = __builtin_elementwise_fma(wr[i*4 + 1], zh[i][1], mm);
          mm = __builtin_elementwise_fma(wr[i*4 + 2], zh[i][2], mm);
          mm = __builtin_elementwise_fma(wr[i*4 + 3], zh[i][3], mm);
          float m = mm.x + mm.y;
          acc += (m + obr[i]);
        }
      }
      zq[(size_t)d*TT] = acc;
    }
  }

  // ---- loss: h==0 waves hold all per-position partials
  if (h == 0) {
#pragma unroll
    for (int off = 32; off >= 1; off >>= 1) lacc += __shfl_down(lacc, off, 64);
    if (p == 0) atomicAdd(lossAcc, lacc);
  }
}

// ------------------------------------------------------------- finalize -----
__global__ void rvq_fin(const double* __restrict__ lossAcc, float* __restrict__ out) {
  float v = (float)(*lossAcc * (1.0 / 1048576.0));  // / (CD*TT) / BB, 2^20 exact
  out[ZQN]     = v;   // commitment_loss
  out[ZQN + 1] = v;   // codebook_loss (bitwise identical in reference)
}

// ---------------------------------------------------------------- launch ----
extern "C" void kernel_launch(void* const* d_in, const int* in_sizes, int n_in,
                              void* d_out, int out_size, void* d_ws, size_t ws_size,
                              hipStream_t stream) {
  const float* z     = (const float*)d_in[0];
  const float* in_v  = (const float*)d_in[1];
  const float* in_g  = (const float*)d_in[2];
  const float* in_b  = (const float*)d_in[3];
  const float* out_v = (const float*)d_in[4];
  const float* out_g = (const float*)d_in[5];
  const float* out_b = (const float*)d_in[6];
  const float* cb    = (const float*)d_in[7];
  const int*   nqp   = (const int*)d_in[8];
  float* out = (float*)d_out;

  float*  ws      = (float*)d_ws;
  double* lossAcc = (double*)d_ws;     // first 16 floats reserved

  int prep1_n = 2*NCB*DD*CD + DD*8 + NCB*CBK;     // 37888
  rvq_prep1<<<(prep1_n + 255)/256, 256, 0, stream>>>(in_v, in_g, out_v, out_g,
                                                     out_b, cb, ws, lossAcc);
  rvq_prep2<<<13, 256, 0, stream>>>(in_b, out_b, ws);
  rvq_quant<<<BT/128, 256, 0, stream>>>(z, cb, nqp, ws, out, lossAcc);
  rvq_fin<<<1, 1, 0, stream>>>(lossAcc, out);
}